// Round 1
// baseline (436.511 us; speedup 1.0000x reference)
//
#include <hip/hip_runtime.h>
#include <hip/hip_bf16.h>
#include <stdint.h>

typedef short bf16x8 __attribute__((ext_vector_type(8)));   // 8 bf16 (4 VGPRs)
typedef float f32x4  __attribute__((ext_vector_type(4)));
typedef unsigned int u32x2 __attribute__((ext_vector_type(2)));
typedef unsigned short u16x4 __attribute__((ext_vector_type(4)));

#define NB  32
#define NQn 1024
#define NKn 2048
#define DHn 64
#define KTILE 128

// exp(-1/20)
#define DECAY_C 0.9512294245007140f
// log2(e)/8  (folds the 1/sqrt(64) scale and the base-2 exp into the gate)
#define L2E_OVER_8 0.18033688011112042f

// float -> bf16 round-nearest-even (inputs finite)
__device__ __forceinline__ unsigned short f2b(float x) {
  unsigned u = __float_as_uint(x);
  u = (u + 0x7FFFu + ((u >> 16) & 1u)) >> 16;
  return (unsigned short)u;
}
__device__ __forceinline__ float b2f(unsigned short h) {
  return __uint_as_float(((unsigned)h) << 16);
}

// ---------------- prep: trace update + hi/lo bf16 split (q and k) ----------
__global__ void prep_tr(const float* __restrict__ spikes, const float* __restrict__ trace,
                        unsigned short* __restrict__ hi, unsigned short* __restrict__ lo, int n4) {
  int i = blockIdx.x * 256 + threadIdx.x;
  if (i >= n4) return;
  f32x4 s = ((const f32x4*)spikes)[i];
  f32x4 t = ((const f32x4*)trace)[i];
  u16x4 h, l;
#pragma unroll
  for (int j = 0; j < 4; ++j) {
    float v = fmaf(DECAY_C, t[j], s[j]);
    unsigned short hb = f2b(v);
    h[j] = hb;
    l[j] = f2b(v - b2f(hb));
  }
  ((u16x4*)hi)[i] = h;
  ((u16x4*)lo)[i] = l;
}

// ---------------- prep: V -> bf16, transposed to [b][dh][k] ----------------
__global__ void prep_vt(const float* __restrict__ value, unsigned short* __restrict__ v_t) {
  __shared__ unsigned short tile[64][80];  // 80-ushort stride: 16B-aligned rows
  const int b = blockIdx.y;
  const int kt = blockIdx.x * 64;
  const int t = threadIdx.x;
  { // read 64k x 64dh f32 tile, coalesced; store transposed (col-swizzled) in LDS
    const int kl = t >> 2, dh0 = (t & 3) * 16;
    const float* src = value + ((size_t)b * NKn + kt + kl) * DHn + dh0;
#pragma unroll
    for (int j4 = 0; j4 < 4; ++j4) {
      f32x4 v = *(const f32x4*)(src + j4 * 4);
#pragma unroll
      for (int e = 0; e < 4; ++e) {
        int dh = dh0 + j4 * 4 + e;
        tile[dh][kl ^ (((dh >> 4) & 3) << 4)] = f2b(v[e]);
      }
    }
  }
  __syncthreads();
  { // write [dh][k] rows, coalesced 128B per row
    const int dh = t >> 2, kc = (t & 3) * 16;
    const int cs = kc ^ (((dh >> 4) & 3) << 4);
    bf16x8 r0 = *(const bf16x8*)&tile[dh][cs];
    bf16x8 r1 = *(const bf16x8*)&tile[dh][cs + 8];
    unsigned short* dst = v_t + ((size_t)b * DHn + dh) * NKn + kt + kc;
    *(bf16x8*)dst = r0;
    *(bf16x8*)(dst + 8) = r1;
  }
}

// ---------------- prep: phase gate table (gate * log2e/8) ------------------
__global__ void prep_gate(const float* __restrict__ key_phases, const float* __restrict__ cur,
                          float* __restrict__ gate2) {
  int k = blockIdx.x * 256 + threadIdx.x;
  if (k >= NKn) return;
  float pd = fabsf(key_phases[k] - cur[0]);
  pd = fminf(pd, 6.28318530717958647f - pd);
  // 1/(2*PHASE_WIDTH^2) = 0.81056946913870
  float gate = expf(-pd * pd * 0.81056946913870f);
  gate2[k] = gate * L2E_OVER_8;
}

// ---------------- main fused attention -------------------------------------
// Block: 256 thr (4 waves). Each wave owns 16 q rows. Swapped MFMA: mfma(K,Q)
// => lane holds S[q = lane&15][k = tile*16 + 4*(lane>>4) + reg].
__launch_bounds__(256, 2)
__global__ void attn_main(const unsigned short* __restrict__ q_hi, const unsigned short* __restrict__ q_lo,
                          const unsigned short* __restrict__ k_hi, const unsigned short* __restrict__ k_lo,
                          const unsigned short* __restrict__ v_t, const float* __restrict__ gate2,
                          float* __restrict__ out, float* __restrict__ attn) {
  __shared__ __attribute__((aligned(16))) unsigned short lds_khi[KTILE * DHn];  // 16KB [k][dh], swizzled
  __shared__ __attribute__((aligned(16))) unsigned short lds_klo[KTILE * DHn];  // 16KB
  __shared__ __attribute__((aligned(16))) unsigned short lds_v[DHn * KTILE];    // 16KB [dh][k], swizzled
  __shared__ __attribute__((aligned(16))) unsigned short lds_p[4][16 * KTILE];  // 16KB per-wave P

  const int b = blockIdx.y;
  const int qt = blockIdx.x;
  const int tid = threadIdx.x;
  const int w = tid >> 6;
  const int l = tid & 63;
  const int c = l & 15;   // q lane (and dh lane / k-row lane)
  const int g = l >> 4;   // 4-lane group
  const int swz = (c & 7) << 4;

  const int qwb = qt * 64 + w * 16;
  const size_t qoff = ((size_t)b * NQn + qwb + c) * DHn;
  bf16x8 qh0 = *(const bf16x8*)(q_hi + qoff + 8 * g);
  bf16x8 qh1 = *(const bf16x8*)(q_hi + qoff + 32 + 8 * g);
  bf16x8 ql0 = *(const bf16x8*)(q_lo + qoff + 8 * g);
  bf16x8 ql1 = *(const bf16x8*)(q_lo + qoff + 32 + 8 * g);

  const unsigned short* khi_b = k_hi + (size_t)b * NKn * DHn;
  const unsigned short* klo_b = k_lo + (size_t)b * NKn * DHn;
  const unsigned short* vt_b  = v_t  + (size_t)b * DHn * NKn;

  float m_run = -3.0e38f, l_run = 0.0f;

  // ---------------- PASS A: online row max & sum ----------------
  for (int kb = 0; kb < NKn; kb += KTILE) {
    __syncthreads();
    // stage k_hi/k_lo rows [w*32, w*32+32), XOR-swizzled
#pragma unroll
    for (int j = 0; j < 4; ++j) {
      const int kr = w * 32 + j * 8 + (l >> 3);
      const int cu = (l & 7) * 8;  // ushort col
      bf16x8 vh = *(const bf16x8*)(khi_b + (size_t)(kb + kr) * DHn + cu);
      bf16x8 vl = *(const bf16x8*)(klo_b + (size_t)(kb + kr) * DHn + cu);
      const int dst = kr * 128 + ((cu * 2) ^ ((kr & 7) << 4));
      *(bf16x8*)((char*)lds_khi + dst) = vh;
      *(bf16x8*)((char*)lds_klo + dst) = vl;
    }
    __syncthreads();
#pragma unroll
    for (int t = 0; t < 8; ++t) {
      const char* rh = (const char*)lds_khi + (t * 16 + c) * 128;
      const char* rl = (const char*)lds_klo + (t * 16 + c) * 128;
      bf16x8 kh0 = *(const bf16x8*)(rh + ((16 * g) ^ swz));
      bf16x8 kh1 = *(const bf16x8*)(rh + ((64 + 16 * g) ^ swz));
      bf16x8 kl0f = *(const bf16x8*)(rl + ((16 * g) ^ swz));
      bf16x8 kl1f = *(const bf16x8*)(rl + ((64 + 16 * g) ^ swz));
      f32x4 acc = {0.f, 0.f, 0.f, 0.f};
      acc = __builtin_amdgcn_mfma_f32_16x16x32_bf16(kh0, qh0, acc, 0, 0, 0);
      acc = __builtin_amdgcn_mfma_f32_16x16x32_bf16(kh1, qh1, acc, 0, 0, 0);
      acc = __builtin_amdgcn_mfma_f32_16x16x32_bf16(kh0, ql0, acc, 0, 0, 0);
      acc = __builtin_amdgcn_mfma_f32_16x16x32_bf16(kh1, ql1, acc, 0, 0, 0);
      acc = __builtin_amdgcn_mfma_f32_16x16x32_bf16(kl0f, qh0, acc, 0, 0, 0);
      acc = __builtin_amdgcn_mfma_f32_16x16x32_bf16(kl1f, qh1, acc, 0, 0, 0);
      const f32x4 gt = *(const f32x4*)(gate2 + kb + t * 16 + 4 * g);
      float s0 = acc[0] * gt[0], s1 = acc[1] * gt[1], s2 = acc[2] * gt[2], s3 = acc[3] * gt[3];
      float tm = fmaxf(fmaxf(s0, s1), fmaxf(s2, s3));
      float mn = fmaxf(m_run, tm);
      l_run = l_run * exp2f(m_run - mn) + exp2f(s0 - mn) + exp2f(s1 - mn) + exp2f(s2 - mn) + exp2f(s3 - mn);
      m_run = mn;
    }
  }
  // combine partials across the 4 lane-groups holding the same q row
#pragma unroll
  for (int off = 16; off <= 32; off <<= 1) {
    float mo = __shfl_xor(m_run, off, 64);
    float lo = __shfl_xor(l_run, off, 64);
    float mn = fmaxf(m_run, mo);
    l_run = l_run * exp2f(m_run - mn) + lo * exp2f(mo - mn);
    m_run = mn;
  }
  const float inv_l = 1.0f / l_run;

  // ---------------- PASS B: recompute, write attn, PV ----------------
  f32x4 oacc[4];
#pragma unroll
  for (int j = 0; j < 4; ++j) oacc[j] = (f32x4){0.f, 0.f, 0.f, 0.f};

  char* plds = (char*)(&lds_p[w][0]);

  for (int kb = 0; kb < NKn; kb += KTILE) {
    __syncthreads();
#pragma unroll
    for (int j = 0; j < 4; ++j) {
      const int kr = w * 32 + j * 8 + (l >> 3);
      const int cu = (l & 7) * 8;
      bf16x8 vh = *(const bf16x8*)(khi_b + (size_t)(kb + kr) * DHn + cu);
      bf16x8 vl = *(const bf16x8*)(klo_b + (size_t)(kb + kr) * DHn + cu);
      const int dst = kr * 128 + ((cu * 2) ^ ((kr & 7) << 4));
      *(bf16x8*)((char*)lds_khi + dst) = vh;
      *(bf16x8*)((char*)lds_klo + dst) = vl;
      // V^T rows [w*16, w*16+16)
      const int dr = w * 16 + j * 4 + (l >> 4);
      const int cv = (l & 15) * 8;
      bf16x8 vv = *(const bf16x8*)(vt_b + (size_t)dr * NKn + kb + cv);
      *(bf16x8*)((char*)lds_v + dr * 256 + ((cv * 2) ^ ((dr & 7) << 4))) = vv;
    }
    __syncthreads();
#pragma unroll
    for (int tp = 0; tp < 4; ++tp) {
#pragma unroll
      for (int u = 0; u < 2; ++u) {
        const int t = tp * 2 + u;
        const char* rh = (const char*)lds_khi + (t * 16 + c) * 128;
        const char* rl = (const char*)lds_klo + (t * 16 + c) * 128;
        bf16x8 kh0 = *(const bf16x8*)(rh + ((16 * g) ^ swz));
        bf16x8 kh1 = *(const bf16x8*)(rh + ((64 + 16 * g) ^ swz));
        bf16x8 kl0f = *(const bf16x8*)(rl + ((16 * g) ^ swz));
        bf16x8 kl1f = *(const bf16x8*)(rl + ((64 + 16 * g) ^ swz));
        f32x4 acc = {0.f, 0.f, 0.f, 0.f};
        acc = __builtin_amdgcn_mfma_f32_16x16x32_bf16(kh0, qh0, acc, 0, 0, 0);
        acc = __builtin_amdgcn_mfma_f32_16x16x32_bf16(kh1, qh1, acc, 0, 0, 0);
        acc = __builtin_amdgcn_mfma_f32_16x16x32_bf16(kh0, ql0, acc, 0, 0, 0);
        acc = __builtin_amdgcn_mfma_f32_16x16x32_bf16(kh1, ql1, acc, 0, 0, 0);
        acc = __builtin_amdgcn_mfma_f32_16x16x32_bf16(kl0f, qh0, acc, 0, 0, 0);
        acc = __builtin_amdgcn_mfma_f32_16x16x32_bf16(kl1f, qh1, acc, 0, 0, 0);
        const f32x4 gt = *(const f32x4*)(gate2 + kb + t * 16 + 4 * g);
        float p0 = exp2f(acc[0] * gt[0] - m_run) * inv_l;
        float p1 = exp2f(acc[1] * gt[1] - m_run) * inv_l;
        float p2 = exp2f(acc[2] * gt[2] - m_run) * inv_l;
        float p3 = exp2f(acc[3] * gt[3] - m_run) * inv_l;
        // write attention (f32, float4, coalesced 64B runs per row)
        const size_t arow = ((size_t)b * NQn + qwb + c) * NKn + kb + t * 16 + 4 * g;
        f32x4 pv = {p0, p1, p2, p3};
        *(f32x4*)(attn + arow) = pv;
        // stash bf16 P for the PV MFMA (per-wave LDS, swizzled)
        u32x2 pw;
        pw[0] = (unsigned)f2b(p0) | ((unsigned)f2b(p1) << 16);
        pw[1] = (unsigned)f2b(p2) | ((unsigned)f2b(p3) << 16);
        *(u32x2*)(plds + c * 256 + ((t * 32 + 8 * g) ^ swz)) = pw;
      }
      // PV over this 32-k slab
      bf16x8 pf = *(const bf16x8*)(plds + c * 256 + ((tp * 64 + 16 * g) ^ swz));
#pragma unroll
      for (int j2 = 0; j2 < 4; ++j2) {
        const int vr = j2 * 16 + c;
        bf16x8 vf = *(const bf16x8*)((const char*)lds_v + vr * 256 + ((tp * 64 + 16 * g) ^ swz));
        oacc[j2] = __builtin_amdgcn_mfma_f32_16x16x32_bf16(pf, vf, oacc[j2], 0, 0, 0);
      }
    }
  }
  // epilogue: out[q = qwb + 4g + r][dh = j2*16 + c]
#pragma unroll
  for (int j2 = 0; j2 < 4; ++j2)
#pragma unroll
    for (int r = 0; r < 4; ++r)
      out[((size_t)b * NQn + qwb + 4 * g + r) * DHn + j2 * 16 + c] = oacc[j2][r];
}

// ---------------------------------------------------------------------------
extern "C" void kernel_launch(void* const* d_in, const int* in_sizes, int n_in,
                              void* d_out, int out_size, void* d_ws, size_t ws_size,
                              hipStream_t stream) {
  const float* q_sp = (const float*)d_in[0];
  const float* k_sp = (const float*)d_in[1];
  const float* val  = (const float*)d_in[2];
  const float* q_tr = (const float*)d_in[3];
  const float* k_tr = (const float*)d_in[4];
  const float* kph  = (const float*)d_in[5];
  const float* cph  = (const float*)d_in[6];

  unsigned short* q_hi = (unsigned short*)d_ws;
  unsigned short* q_lo = q_hi + (size_t)NB * NQn * DHn;
  unsigned short* k_hi = q_lo + (size_t)NB * NQn * DHn;
  unsigned short* k_lo = k_hi + (size_t)NB * NKn * DHn;
  unsigned short* v_t  = k_lo + (size_t)NB * NKn * DHn;
  float* gate2 = (float*)(v_t + (size_t)NB * NKn * DHn);

  float* out = (float*)d_out;
  float* attn = out + (size_t)NB * NQn * DHn;

  const int nq4 = NB * NQn * DHn / 4;
  const int nk4 = NB * NKn * DHn / 4;
  prep_tr<<<dim3(nq4 / 256), 256, 0, stream>>>(q_sp, q_tr, q_hi, q_lo, nq4);
  prep_tr<<<dim3(nk4 / 256), 256, 0, stream>>>(k_sp, k_tr, k_hi, k_lo, nk4);
  prep_vt<<<dim3(NKn / 64, NB), 256, 0, stream>>>(val, v_t);
  prep_gate<<<dim3(NKn / 256), 256, 0, stream>>>(kph, cph, gate2);
  attn_main<<<dim3(NQn / 64, NB), 256, 0, stream>>>(q_hi, q_lo, k_hi, k_lo, v_t, gate2, out, attn);
}